// Round 9
// baseline (833.364 us; speedup 1.0000x reference)
//
#include <hip/hip_runtime.h>
#include <stdint.h>

// Problem dims (fixed by the reference)
#define TT 256
#define SS 256
#define FF 1024
#define AA 256

typedef __attribute__((ext_vector_type(8))) short short8;
typedef __attribute__((ext_vector_type(8))) unsigned short ushort8v;
typedef __attribute__((ext_vector_type(4))) float floatx4;

// fp32 -> bf16 round-to-nearest-even
__device__ __forceinline__ unsigned short f2bf(float f) {
  unsigned int u = __float_as_uint(f);
  u += 0x7FFFu + ((u >> 16) & 1u);
  return (unsigned short)(u >> 16);
}

// async global->LDS, 16 B per lane; LDS dest = wave-uniform base + lane*16
__device__ __forceinline__ void gl_lds16(const unsigned short* g, unsigned short* l) {
  __builtin_amdgcn_global_load_lds(
      (__attribute__((address_space(1))) void*)(g),
      (__attribute__((address_space(3))) void*)(l), 16, 0, 0);
}

// swizzled LDS fragment read: logical (row, 16B-chunk lq) of a [R][32] bf16
// tile; phys byte = logical ^ ((bit9)<<5)  (st_16x32; 0 conflicts measured
// at this 64B row stride — do NOT reuse for other strides, see R7 lesson)
__device__ __forceinline__ short8 frag_ld(const unsigned short* base, int row,
                                          int lq) {
  unsigned l = (unsigned)(row * 64 + lq * 16);
  l ^= ((l >> 9) & 1u) << 5;
  return *(const short8*)((const char*)base + l);
}

// ---------------------------------------------------------------------------
// Fused prep: ONE launch does batch fp32->bf16 cvt (blocks 0..2047) and the
// three weight transposes WT[n][k] = bf16(W[k][n]) (blocks 2048..3583).
// ---------------------------------------------------------------------------
__global__ __launch_bounds__(256) void k_prep(
    const float* __restrict__ batch, const float* __restrict__ a_w,
    const float* __restrict__ b_w, const float* __restrict__ g_w,
    unsigned short* __restrict__ aT, unsigned short* __restrict__ bT,
    unsigned short* __restrict__ gT, unsigned short* __restrict__ batch16) {
  __shared__ float tile[32][33];
  const int b = blockIdx.x;
  const int tid = threadIdx.x;

  if (b < 2048) {
    const long n8 = (long)TT * SS * FF / 8;
    long i = (long)b * 256 + tid;
    const long stride = 2048L * 256;
    for (; i < n8; i += stride) {
      const floatx4 v0 = *(const floatx4*)(batch + i * 8);
      const floatx4 v1 = *(const floatx4*)(batch + i * 8 + 4);
      ushort8v h;
      h[0] = f2bf(v0.x); h[1] = f2bf(v0.y); h[2] = f2bf(v0.z); h[3] = f2bf(v0.w);
      h[4] = f2bf(v1.x); h[5] = f2bf(v1.y); h[6] = f2bf(v1.z); h[7] = f2bf(v1.w);
      *(ushort8v*)(batch16 + i * 8) = h;
    }
    return;
  }

  int tb = b - 2048;
  const float* W;
  unsigned short* WT;
  int N, bk, bn;
  if (tb < 256)      { W = a_w; WT = aT; N = AA; bk = (tb & 31) * 32; bn = (tb >> 5) * 32; }
  else if (tb < 512) { tb -= 256; W = b_w; WT = bT; N = AA; bk = (tb & 31) * 32; bn = (tb >> 5) * 32; }
  else               { tb -= 512; W = g_w; WT = gT; N = FF; bk = (tb & 31) * 32; bn = (tb >> 5) * 32; }
  const int K = FF;
  const int tx = tid & 31, ty = tid >> 5;
  for (int i = ty; i < 32; i += 8)
    tile[i][tx] = W[(size_t)(bk + i) * N + bn + tx];
  __syncthreads();
  for (int i = ty; i < 32; i += 8)
    WT[(size_t)(bn + i) * K + bk + tx] = f2bf(tile[tx][i]);
}

// ---------------------------------------------------------------------------
// Weight transpose (fallback path only).
// ---------------------------------------------------------------------------
__global__ void k_transpose_cvt(const float* __restrict__ W,
                                unsigned short* __restrict__ WT,
                                int K, int N) {
  __shared__ float tile[32][33];
  const int bk = blockIdx.x * 32, bn = blockIdx.y * 32;
  const int tx = threadIdx.x, ty = threadIdx.y;
  for (int i = ty; i < 32; i += 8)
    tile[i][tx] = W[(size_t)(bk + i) * N + bn + tx];
  __syncthreads();
  for (int i = ty; i < 32; i += 8)
    WT[(size_t)(bn + i) * K + bk + tx] = f2bf(tile[tx][i]);
}

// ---------------------------------------------------------------------------
// Projection GEMM, 256x256 tile, software-pipelined single-barrier K-loop
// (R6/R8 VERIFIED VERSION — unchanged).
// ---------------------------------------------------------------------------
__global__ __launch_bounds__(512, 2) void k_proj8(
    const unsigned short* __restrict__ batch16,
    const unsigned short* __restrict__ aT,
    const unsigned short* __restrict__ bT,
    const unsigned short* __restrict__ gT,
    const float* __restrict__ a_b, const float* __restrict__ b_b,
    const float* __restrict__ g_b,
    unsigned short* __restrict__ theta,
    unsigned short* __restrict__ phi,
    unsigned short* __restrict__ featsT) {
  const int K = FF;  // 1024
  __shared__ unsigned short Al[3][2][4096];  // [slot][m-half][128*32]
  __shared__ unsigned short Bl[3][2][4096];  // [slot][n-half][128*32]

  const int lin = blockIdx.x;
  const int xcd = lin & 7, idx = lin >> 3;
  const int nt = idx % 6;
  const int mt = xcd * 32 + idx / 6;
  const int m0 = mt * 256;

  const unsigned short* Wt;
  const float* bias;
  int mode, nf0 = 0;  // mode: 0 theta, 1 phi, 2 featsT
  if (nt == 0)      { Wt = aT; bias = a_b; mode = 0; }
  else if (nt == 1) { Wt = bT; bias = b_b; mode = 1; }
  else { nf0 = (nt - 2) * 256; Wt = gT + (size_t)nf0 * K; bias = g_b + nf0; mode = 2; }

  const int tid = threadIdx.x;
  const int lane = tid & 63, wave = tid >> 6;
  const int wm = wave >> 2, wn = wave & 3;   // 2 x 4 wave grid
  const int lr = lane & 15, lq = lane >> 4;
  const int bh = wn >> 1;
  const int bn0 = (wn & 1) * 64;

  const unsigned o = (unsigned)tid * 16u;
  const unsigned lo = o ^ (((o >> 9) & 1u) << 5);
  const int srow = (int)(lo >> 6);
  const int scol = (int)((lo & 63u) >> 1);
  const unsigned aoff = (unsigned)(srow * K + scol);
  const int ldsb = wave * 512;

  const unsigned short* pA0 = batch16 + (size_t)m0 * K;
  const unsigned short* pA1 = pA0 + (size_t)128 * K;
  const unsigned short* pB0 = Wt;
  const unsigned short* pB1 = Wt + (size_t)128 * K;

  floatx4 acc[8][4];
#pragma unroll
  for (int i = 0; i < 8; i++)
#pragma unroll
    for (int j = 0; j < 4; j++) acc[i][j] = (floatx4)0.0f;

  short8 fA0[8], fB0[4], fA1[8], fB1[4];

  gl_lds16(pA0 + aoff + 0, &Al[0][0][ldsb]);
  gl_lds16(pA1 + aoff + 0, &Al[0][1][ldsb]);
  gl_lds16(pB0 + aoff + 0, &Bl[0][0][ldsb]);
  gl_lds16(pB1 + aoff + 0, &Bl[0][1][ldsb]);
  gl_lds16(pA0 + aoff + 32, &Al[1][0][ldsb]);
  gl_lds16(pA1 + aoff + 32, &Al[1][1][ldsb]);
  gl_lds16(pB0 + aoff + 32, &Bl[1][0][ldsb]);
  gl_lds16(pB1 + aoff + 32, &Bl[1][1][ldsb]);
  asm volatile("s_waitcnt vmcnt(4)" ::: "memory");
  __builtin_amdgcn_s_barrier();
#pragma unroll
  for (int i = 0; i < 8; i++)
    fA0[i] = frag_ld(Al[0][wm], ((i >> 2) * 64) + (i & 3) * 16 + lr, lq);
#pragma unroll
  for (int i = 0; i < 4; i++)
    fB0[i] = frag_ld(Bl[0][bh], bn0 + i * 16 + lr, lq);
  gl_lds16(pA0 + aoff + 64, &Al[2][0][ldsb]);
  gl_lds16(pA1 + aoff + 64, &Al[2][1][ldsb]);
  gl_lds16(pB0 + aoff + 64, &Bl[2][0][ldsb]);
  gl_lds16(pB1 + aoff + 64, &Bl[2][1][ldsb]);
  asm volatile("s_waitcnt lgkmcnt(0)" ::: "memory");
  __builtin_amdgcn_sched_barrier(0);
  asm volatile("s_waitcnt vmcnt(4)" ::: "memory");
  __builtin_amdgcn_s_barrier();

  int slR = 1, slW = 0, kst = 96;

#define PBODY(CA, CB, NA, NB, DOSTG, VM)                                     \
  do {                                                                       \
    const unsigned short* Ah_ = Al[slR][wm];                                 \
    const unsigned short* Bh_ = Bl[slR][bh];                                 \
    _Pragma("unroll") for (int i_ = 0; i_ < 8; i_++)                         \
        NA[i_] = frag_ld(Ah_, ((i_ >> 2) * 64) + (i_ & 3) * 16 + lr, lq);    \
    _Pragma("unroll") for (int i_ = 0; i_ < 4; i_++)                         \
        NB[i_] = frag_ld(Bh_, bn0 + i_ * 16 + lr, lq);                       \
    if (DOSTG) {                                                             \
      gl_lds16(pA0 + aoff + kst, &Al[slW][0][ldsb]);                         \
      gl_lds16(pA1 + aoff + kst, &Al[slW][1][ldsb]);                         \
      gl_lds16(pB0 + aoff + kst, &Bl[slW][0][ldsb]);                         \
      gl_lds16(pB1 + aoff + kst, &Bl[slW][1][ldsb]);                         \
    }                                                                        \
    __builtin_amdgcn_s_setprio(1);                                           \
    _Pragma("unroll") for (int i_ = 0; i_ < 8; i_++)                         \
      _Pragma("unroll") for (int j_ = 0; j_ < 4; j_++)                       \
          acc[i_][j_] = __builtin_amdgcn_mfma_f32_16x16x32_bf16(             \
              CA[i_], CB[j_], acc[i_][j_], 0, 0, 0);                         \
    __builtin_amdgcn_s_setprio(0);                                           \
    asm volatile("s_waitcnt lgkmcnt(0)" ::: "memory");                       \
    __builtin_amdgcn_sched_barrier(0);                                       \
    asm volatile("s_waitcnt vmcnt(" VM ")" ::: "memory");                    \
    __builtin_amdgcn_s_barrier();                                            \
    slW = slR; slR = (slR == 2) ? 0 : slR + 1; kst += 32;                    \
  } while (0)

  for (int jt = 0; jt < 14; ++jt) {
    PBODY(fA0, fB0, fA1, fB1, 1, "4");
    PBODY(fA1, fB1, fA0, fB0, 1, "4");
  }
  PBODY(fA0, fB0, fA1, fB1, 1, "4");
  PBODY(fA1, fB1, fA0, fB0, 0, "0");
  PBODY(fA0, fB0, fA1, fB1, 0, "0");
  __builtin_amdgcn_s_setprio(1);
#pragma unroll
  for (int i = 0; i < 8; i++)
#pragma unroll
    for (int j = 0; j < 4; j++)
      acc[i][j] = __builtin_amdgcn_mfma_f32_16x16x32_bf16(fA1[i], fB1[j],
                                                          acc[i][j], 0, 0, 0);
  __builtin_amdgcn_s_setprio(0);
#undef PBODY

  if (mode == 2) {
#pragma unroll
    for (int r = 0; r < 8; r++) {
      const int s0 = wm * 128 + r * 16 + lq * 4;
#pragma unroll
      for (int jj = 0; jj < 4; jj++) {
        const int cl = wn * 64 + jj * 16 + lr;
        const float bv = bias[cl];
        ushort4 h;
        h.x = f2bf(acc[r][jj][0] + bv);
        h.y = f2bf(acc[r][jj][1] + bv);
        h.z = f2bf(acc[r][jj][2] + bv);
        h.w = f2bf(acc[r][jj][3] + bv);
        *(ushort4*)&featsT[((size_t)mt * FF + nf0 + cl) * SS + s0] = h;
      }
    }
  } else {
    unsigned short* outp = (mode == 0) ? theta : phi;
#pragma unroll
    for (int r = 0; r < 8; r++) {
      const int row0 = m0 + wm * 128 + r * 16 + lq * 4;
#pragma unroll
      for (int jj = 0; jj < 4; jj++) {
        const int col = wn * 64 + jj * 16 + lr;
        const float bv = bias[col];
#pragma unroll
        for (int rr = 0; rr < 4; rr++)
          outp[(size_t)(row0 + rr) * AA + col] = f2bf(acc[r][jj][rr] + bv);
      }
    }
  }
}

// ---------------------------------------------------------------------------
// Fused projection GEMM, fp32-A FALLBACK (used only if workspace too small).
// ---------------------------------------------------------------------------
__global__ __launch_bounds__(256) void k_proj(
    const float* __restrict__ batch,
    const unsigned short* __restrict__ aT,
    const unsigned short* __restrict__ bT,
    const unsigned short* __restrict__ gT,
    const float* __restrict__ a_b, const float* __restrict__ b_b,
    const float* __restrict__ g_b,
    unsigned short* __restrict__ theta,
    unsigned short* __restrict__ phi,
    unsigned short* __restrict__ featsT) {
  const int K = FF;
  __shared__ unsigned short As[128 * 32];
  __shared__ unsigned short Bs[128 * 32];

  const int nt = blockIdx.x, mt = blockIdx.y;
  const int m0 = mt * 128;
  const unsigned short* Wt;
  const float* bias;
  int nloc0, mode;
  if (nt < 2)      { Wt = aT; bias = a_b; nloc0 = nt * 128;       mode = 0; }
  else if (nt < 4) { Wt = bT; bias = b_b; nloc0 = (nt - 2) * 128; mode = 1; }
  else             { Wt = gT; bias = g_b; nloc0 = (nt - 4) * 128; mode = 2; }

  const int tid = threadIdx.x;
  const int lane = tid & 63, wave = tid >> 6;
  const int wm = wave >> 1, wn = wave & 1;
  const int lr = lane & 15, lq = lane >> 4;

  floatx4 acc[4][4];
#pragma unroll
  for (int i = 0; i < 4; i++)
#pragma unroll
    for (int j = 0; j < 4; j++) acc[i][j] = (floatx4)0.0f;

  for (int k0 = 0; k0 < K; k0 += 32) {
    __syncthreads();
    {
      int sl = tid;
      gl_lds16(Wt + (size_t)(nloc0 + (sl >> 2)) * K + k0 + (sl & 3) * 8,
               &Bs[wave * 512]);
      sl = tid + 256;
      gl_lds16(Wt + (size_t)(nloc0 + (sl >> 2)) * K + k0 + (sl & 3) * 8,
               &Bs[2048 + wave * 512]);
    }
#pragma unroll
    for (int sgi = 0; sgi < 4; sgi++) {
      int g = sgi * 256 + tid;
      int row = g >> 3, c4 = g & 7;
      const floatx4 v =
          *(const floatx4*)(batch + (size_t)(m0 + row) * K + k0 + c4 * 4);
      ushort4 h;
      h.x = f2bf(v.x); h.y = f2bf(v.y); h.z = f2bf(v.z); h.w = f2bf(v.w);
      *(ushort4*)&As[row * 32 + c4 * 4] = h;
    }
    __syncthreads();

    short8 af[4], bfr[4];
#pragma unroll
    for (int i = 0; i < 4; i++)
      af[i] = *(const short8*)&As[(wm * 64 + i * 16 + lr) * 32 + lq * 8];
#pragma unroll
    for (int j = 0; j < 4; j++)
      bfr[j] = *(const short8*)&Bs[(wn * 64 + j * 16 + lr) * 32 + lq * 8];
#pragma unroll
    for (int i = 0; i < 4; i++)
#pragma unroll
      for (int j = 0; j < 4; j++)
        acc[i][j] = __builtin_amdgcn_mfma_f32_16x16x32_bf16(af[i], bfr[j],
                                                            acc[i][j], 0, 0, 0);
  }

#pragma unroll
  for (int i = 0; i < 4; i++) {
    const int row0 = wm * 64 + i * 16 + lq * 4;
#pragma unroll
    for (int j = 0; j < 4; j++) {
      const int col = wn * 64 + j * 16 + lr;
      const float bv = bias[nloc0 + col];
      if (mode == 2) {
        const int m = m0 + row0;
        const int t = m >> 8, s = m & 255;
        ushort4 h;
        h.x = f2bf(acc[i][j][0] + bv);
        h.y = f2bf(acc[i][j][1] + bv);
        h.z = f2bf(acc[i][j][2] + bv);
        h.w = f2bf(acc[i][j][3] + bv);
        *(ushort4*)&featsT[((size_t)t * FF + nloc0 + col) * SS + s] = h;
      } else {
        unsigned short* outp = (mode == 0) ? theta : phi;
#pragma unroll
        for (int rr = 0; rr < 4; rr++)
          outp[(size_t)(m0 + row0 + rr) * AA + nloc0 + col] =
              f2bf(acc[i][j][rr] + bv);
      }
    }
  }
}

// ---------------------------------------------------------------------------
// Fused attn+apply v3: 1024 blocks x 256 threads (4 waves, 1x4 n-split).
// Block owns 64 attn rows (t, q): P = theta[t][q*64..][:] @ phi[t]^T, then
// out = P @ featsT[t]^T / 512. Same schedule pattern / swizzles / arithmetic
// order as verified k_fused2, but LDS = 32 KB P + 48 KB ring = 80 KB ->
// ** 2 blocks/CU ** so two independent pipelines overlap each other's
// vmcnt/barrier stalls (proj8's proven hiding mechanism).
//   Phase 1: 8 k-tiles {A 4KB + B 16KB = 5 gl_lds16/thread}, 2-slot dbuf
//            (20 KB slots), counted vmcnt(5).
//   Phase 2: 32 tiles {B 16KB = 4 gl_lds16/thread}, 3-slot ring, counted
//            vmcnt(4); wait SKIPPED at T%8 in {0,1}, T>=8 (64 chunk-end
//            stores exceed the 63-entry VMEM queue -> older loads provably
//            retired; waiting would drain the store queue).
// All LDS tiles are [R][32] bf16 (64B row stride) with the VERIFIED st_16x32
// swizzle; P is [64][256] with the verified (row&7)<<4 swizzle.
// ---------------------------------------------------------------------------
__global__ __launch_bounds__(256) void k_fused3(
    const unsigned short* __restrict__ theta,
    const unsigned short* __restrict__ phi,
    const unsigned short* __restrict__ featsT,
    float* __restrict__ out) {
  __shared__ unsigned short ring[24576];  // 48 KB
  __shared__ unsigned short P[64 * 256];  // 32 KB, swizzled

  // XCD map (round-robin dispatch): 1024 = 8 xcd * 32 t * 4 q; the 4 q-blocks
  // of one t are adjacent on one XCD -> featsT[t]/phi[t] L2-shared 4-way.
  const int lin = blockIdx.x;
  const int xcd = lin & 7, idx = lin >> 3;  // idx in [0,128)
  const int t = xcd * 32 + (idx >> 2);
  const int q = idx & 3;

  const int tid = threadIdx.x, lane = tid & 63, wn = tid >> 6;  // wave = wn
  const int lr = lane & 15, lq = lane >> 4;

  const unsigned short* thq = theta + ((size_t)t * SS + q * 64) * AA;
  const unsigned short* ph = phi + (size_t)t * SS * AA;
  const unsigned short* ft = featsT + (size_t)t * FF * SS;

  // Inverse-swizzled source coords. A tile: [64][32] (4 KB, 1 call).
  // B tiles: [256][32] (16 KB, 4 calls c, byte = c*4096 + tid*16).
  const unsigned oA = (unsigned)tid * 16u;
  const unsigned loA = oA ^ (((oA >> 9) & 1u) << 5);
  const int srA = (int)(loA >> 6), scA = (int)((loA & 63u) >> 1);
  int srB[4], scB[4];
#pragma unroll
  for (int c = 0; c < 4; c++) {
    const unsigned ob = (unsigned)(c * 4096) + (unsigned)tid * 16u;
    const unsigned lob = ob ^ (((ob >> 9) & 1u) << 5);
    srB[c] = (int)(lob >> 6);
    scB[c] = (int)((lob & 63u) >> 1);
  }
  const int ldsb = wn * 512;  // wave-uniform dest base (elems) within a call

  // ======== Phase 1: attn tile (64x256) -> P ========
  // slot s (20 KB = 10240 elems): A at +0 (2048 elems), B at +2048 (8192).
#define STG_F1(s_, k_)                                                       \
  do {                                                                       \
    gl_lds16(thq + (size_t)srA * AA + (k_) + scA,                            \
             &ring[(s_)*10240 + ldsb]);                                      \
    _Pragma("unroll") for (int c = 0; c < 4; c++)                            \
        gl_lds16(ph + (size_t)srB[c] * AA + (k_) + scB[c],                   \
                 &ring[(s_)*10240 + 2048 + c * 2048 + ldsb]);                \
  } while (0)

  floatx4 acc[4][4];
#pragma unroll
  for (int i = 0; i < 4; i++)
#pragma unroll
    for (int j = 0; j < 4; j++) acc[i][j] = (floatx4)0.0f;

  STG_F1(0, 0);
  STG_F1(1, 32);
  for (int k = 0; k < 8; ++k) {
    if (k < 7)
      asm volatile("s_waitcnt vmcnt(5)" ::: "memory");  // tile k's 5 landed
    else
      asm volatile("s_waitcnt vmcnt(0)" ::: "memory");
    __builtin_amdgcn_s_barrier();

    const unsigned short* Ab = &ring[(k & 1) * 10240];
    const unsigned short* Bb = Ab + 2048;
    short8 af[4], bf4[4];
#pragma unroll
    for (int i = 0; i < 4; i++) af[i] = frag_ld(Ab, i * 16 + lr, lq);
#pragma unroll
    for (int j = 0; j < 4; j++)
      bf4[j] = frag_ld(Bb, wn * 64 + j * 16 + lr, lq);
    asm volatile("s_waitcnt lgkmcnt(0)" ::: "memory");  // reads done ...
    __builtin_amdgcn_s_barrier();                        // ... for ALL waves
    if (k < 6) STG_F1(k & 1, (k + 2) * 32);              // overwrite cur slot

    __builtin_amdgcn_s_setprio(1);
#pragma unroll
    for (int i = 0; i < 4; i++)
#pragma unroll
      for (int j = 0; j < 4; j++)
        acc[i][j] = __builtin_amdgcn_mfma_f32_16x16x32_bf16(af[i], bf4[j],
                                                            acc[i][j], 0, 0, 0);
    __builtin_amdgcn_s_setprio(0);
  }
#undef STG_F1

  // Write attn tile to P (bf16, swizzled). C/D: col = lr, row = lq*4 + rr.
#pragma unroll
  for (int i = 0; i < 4; i++) {
#pragma unroll
    for (int j = 0; j < 4; j++) {
      const int colP = wn * 64 + j * 16 + lr;
#pragma unroll
      for (int rr = 0; rr < 4; rr++) {
        const int rowP = i * 16 + lq * 4 + rr;
        const unsigned off =
            ((unsigned)(rowP * 256 + colP) * 2u) ^ ((unsigned)(rowP & 7) << 4);
        *(unsigned short*)((char*)P + off) = f2bf(acc[i][j][rr]);
      }
    }
  }
  __syncthreads();  // P published; all phase-1 ring reads complete

  // ======== Phase 2: out = P @ featsT^T / 512 ========
  // 32 tiles T = c*8 + k (c = f-chunk of 256 rows, k = k-subtile of 32).
  // slot = T % 3, 16 KB each (8192 elems).
#define STG_F2(slot_, T_)                                                    \
  do {                                                                       \
    const int c_ = (T_) >> 3, k_ = ((T_)&7) * 32;                            \
    _Pragma("unroll") for (int c = 0; c < 4; c++)                            \
        gl_lds16(ft + (size_t)(c_ * 256 + srB[c]) * SS + k_ + scB[c],        \
                 &ring[(slot_)*8192 + c * 2048 + ldsb]);                     \
  } while (0)

  STG_F2(0, 0);
  STG_F2(1, 1);

  const float inv = 1.0f / 512.0f;
  float* Ob = out + ((size_t)t * SS + q * 64) * FF;

#pragma unroll
  for (int i = 0; i < 4; i++)
#pragma unroll
    for (int j = 0; j < 4; j++) acc[i][j] = (floatx4)0.0f;

  int slot = 0, slot2 = 2;
  for (int T = 0; T < 32; ++T) {
    if (T == 31) {
      asm volatile("s_waitcnt vmcnt(0)" ::: "memory");
    } else if (!(T >= 8 && (T & 7) < 2)) {
      asm volatile("s_waitcnt vmcnt(4)" ::: "memory");  // tile T landed
    }
    // else: skip — chunk-end stores guarantee STG(T) retired (see header)
    __builtin_amdgcn_s_barrier();

    const int k0 = (T & 7) * 32;
    const unsigned short* Bb = &ring[slot * 8192];
    short8 af[4], bf4[4];
#pragma unroll
    for (int i = 0; i < 4; i++) {
      const int rowP = i * 16 + lr;
      const unsigned off = ((unsigned)(rowP * 256 + k0 + lq * 8) * 2u) ^
                           ((unsigned)(rowP & 7) << 4);
      af[i] = *(const short8*)((const char*)P + off);
    }
#pragma unroll
    for (int j = 0; j < 4; j++)
      bf4[j] = frag_ld(Bb, wn * 64 + j * 16 + lr, lq);
    if (T + 2 < 32) STG_F2(slot2, T + 2);  // targets slot of T-1 (reads done)

    __builtin_amdgcn_s_setprio(1);
#pragma unroll
    for (int i = 0; i < 4; i++)
#pragma unroll
      for (int j = 0; j < 4; j++)
        acc[i][j] = __builtin_amdgcn_mfma_f32_16x16x32_bf16(af[i], bf4[j],
                                                            acc[i][j], 0, 0, 0);
    __builtin_amdgcn_s_setprio(0);

    if ((T & 7) == 7) {  // f-chunk complete: write out, reset acc
      const int c = T >> 3;
#pragma unroll
      for (int i = 0; i < 4; i++) {
        const int row0 = i * 16 + lq * 4;
#pragma unroll
        for (int j = 0; j < 4; j++) {
          const int col = c * 256 + wn * 64 + j * 16 + lr;
#pragma unroll
          for (int rr = 0; rr < 4; rr++)
            Ob[(size_t)(row0 + rr) * FF + col] = acc[i][j][rr] * inv;
          acc[i][j] = (floatx4)0.0f;
        }
      }
    }
    slot = (slot == 2) ? 0 : slot + 1;
    slot2 = (slot2 == 2) ? 0 : slot2 + 1;
  }
#undef STG_F2
}

// ---------------------------------------------------------------------------
extern "C" void kernel_launch(void* const* d_in, const int* in_sizes, int n_in,
                              void* d_out, int out_size, void* d_ws,
                              size_t ws_size, hipStream_t stream) {
  const float* batch = (const float*)d_in[0];
  const float* a_w   = (const float*)d_in[1];
  const float* a_b   = (const float*)d_in[2];
  const float* b_w   = (const float*)d_in[3];
  const float* b_b   = (const float*)d_in[4];
  const float* g_w   = (const float*)d_in[5];
  const float* g_b   = (const float*)d_in[6];
  float* out = (float*)d_out;

  // Workspace layout (bf16 elements).
  unsigned short* ws      = (unsigned short*)d_ws;
  unsigned short* aT      = ws;                                  // 256x1024
  unsigned short* bT      = aT + (size_t)AA * FF;                // 256x1024
  unsigned short* gT      = bT + (size_t)AA * FF;                // 1024x1024
  unsigned short* theta   = gT + (size_t)FF * FF;                // 65536x256
  unsigned short* phi     = theta + (size_t)TT * SS * AA;        // 65536x256
  unsigned short* featsT  = phi + (size_t)TT * SS * AA;          // [t][f][s]
  unsigned short* batch16 = featsT + (size_t)TT * FF * SS;       // 65536x1024

  const size_t need_b16 =
      ((size_t)2 * AA * FF + (size_t)FF * FF + (size_t)2 * TT * SS * AA +
       (size_t)TT * FF * SS + (size_t)TT * SS * FF) *
      sizeof(unsigned short);

  if (ws_size >= need_b16) {
    // One fused prep launch (cvt + 3 transposes), then pipelined 256^2 GEMM.
    k_prep<<<dim3(3584), 256, 0, stream>>>(batch, a_w, b_w, g_w, aT, bT, gT,
                                           batch16);
    k_proj8<<<dim3(1536), 512, 0, stream>>>(batch16, aT, bT, gT, a_b, b_b,
                                            g_b, theta, phi, featsT);
  } else {
    // Fallback: fp32 in-kernel staging (previous verified path).
    dim3 tb(32, 8);
    k_transpose_cvt<<<dim3(32, 8),  tb, 0, stream>>>(a_w, aT, FF, AA);
    k_transpose_cvt<<<dim3(32, 8),  tb, 0, stream>>>(b_w, bT, FF, AA);
    k_transpose_cvt<<<dim3(32, 32), tb, 0, stream>>>(g_w, gT, FF, FF);
    k_proj<<<dim3(12, 512), 256, 0, stream>>>(batch, aT, bT, gT, a_b, b_b,
                                              g_b, theta, phi, featsT);
  }

  // Fused attn + apply v3: 2 blocks/CU, cross-block stall hiding.
  k_fused3<<<dim3(1024), 256, 0, stream>>>(theta, phi, featsT, out);
}

// Round 10
// 833.364 us; speedup vs baseline: 1.0000x; 1.0000x over previous
//
#include <hip/hip_runtime.h>
#include <stdint.h>

// Problem dims (fixed by the reference)
#define TT 256
#define SS 256
#define FF 1024
#define AA 256

typedef __attribute__((ext_vector_type(8))) short short8;
typedef __attribute__((ext_vector_type(8))) unsigned short ushort8v;
typedef __attribute__((ext_vector_type(4))) float floatx4;

// fp32 -> bf16 round-to-nearest-even
__device__ __forceinline__ unsigned short f2bf(float f) {
  unsigned int u = __float_as_uint(f);
  u += 0x7FFFu + ((u >> 16) & 1u);
  return (unsigned short)(u >> 16);
}

// async global->LDS, 16 B per lane; LDS dest = wave-uniform base + lane*16
__device__ __forceinline__ void gl_lds16(const unsigned short* g, unsigned short* l) {
  __builtin_amdgcn_global_load_lds(
      (__attribute__((address_space(1))) void*)(g),
      (__attribute__((address_space(3))) void*)(l), 16, 0, 0);
}

// swizzled LDS fragment read: logical (row, 16B-chunk lq) of a [R][32] bf16
// tile; phys byte = logical ^ ((bit9)<<5)  (st_16x32; 0 conflicts measured
// at this 64B row stride — do NOT reuse for other strides, see R7 lesson)
__device__ __forceinline__ short8 frag_ld(const unsigned short* base, int row,
                                          int lq) {
  unsigned l = (unsigned)(row * 64 + lq * 16);
  l ^= ((l >> 9) & 1u) << 5;
  return *(const short8*)((const char*)base + l);
}

// ---------------------------------------------------------------------------
// Fused prep: ONE launch does batch fp32->bf16 cvt (blocks 0..2047) and the
// three weight transposes WT[n][k] = bf16(W[k][n]) (blocks 2048..3583).
// ---------------------------------------------------------------------------
__global__ __launch_bounds__(256) void k_prep(
    const float* __restrict__ batch, const float* __restrict__ a_w,
    const float* __restrict__ b_w, const float* __restrict__ g_w,
    unsigned short* __restrict__ aT, unsigned short* __restrict__ bT,
    unsigned short* __restrict__ gT, unsigned short* __restrict__ batch16) {
  __shared__ float tile[32][33];
  const int b = blockIdx.x;
  const int tid = threadIdx.x;

  if (b < 2048) {
    const long n8 = (long)TT * SS * FF / 8;
    long i = (long)b * 256 + tid;
    const long stride = 2048L * 256;
    for (; i < n8; i += stride) {
      const floatx4 v0 = *(const floatx4*)(batch + i * 8);
      const floatx4 v1 = *(const floatx4*)(batch + i * 8 + 4);
      ushort8v h;
      h[0] = f2bf(v0.x); h[1] = f2bf(v0.y); h[2] = f2bf(v0.z); h[3] = f2bf(v0.w);
      h[4] = f2bf(v1.x); h[5] = f2bf(v1.y); h[6] = f2bf(v1.z); h[7] = f2bf(v1.w);
      *(ushort8v*)(batch16 + i * 8) = h;
    }
    return;
  }

  int tb = b - 2048;
  const float* W;
  unsigned short* WT;
  int N, bk, bn;
  if (tb < 256)      { W = a_w; WT = aT; N = AA; bk = (tb & 31) * 32; bn = (tb >> 5) * 32; }
  else if (tb < 512) { tb -= 256; W = b_w; WT = bT; N = AA; bk = (tb & 31) * 32; bn = (tb >> 5) * 32; }
  else               { tb -= 512; W = g_w; WT = gT; N = FF; bk = (tb & 31) * 32; bn = (tb >> 5) * 32; }
  const int K = FF;
  const int tx = tid & 31, ty = tid >> 5;
  for (int i = ty; i < 32; i += 8)
    tile[i][tx] = W[(size_t)(bk + i) * N + bn + tx];
  __syncthreads();
  for (int i = ty; i < 32; i += 8)
    WT[(size_t)(bn + i) * K + bk + tx] = f2bf(tile[tx][i]);
}

// ---------------------------------------------------------------------------
// Weight transpose (fallback path only).
// ---------------------------------------------------------------------------
__global__ void k_transpose_cvt(const float* __restrict__ W,
                                unsigned short* __restrict__ WT,
                                int K, int N) {
  __shared__ float tile[32][33];
  const int bk = blockIdx.x * 32, bn = blockIdx.y * 32;
  const int tx = threadIdx.x, ty = threadIdx.y;
  for (int i = ty; i < 32; i += 8)
    tile[i][tx] = W[(size_t)(bk + i) * N + bn + tx];
  __syncthreads();
  for (int i = ty; i < 32; i += 8)
    WT[(size_t)(bn + i) * K + bk + tx] = f2bf(tile[tx][i]);
}

// ---------------------------------------------------------------------------
// Projection GEMM v4: SAME verified PBODY schedule as R6/R8 proj8, reshaped
// for 2 blocks/CU: 4 waves (1M x 4N), tile 128x256, 3-slot ring of
// {A [128][32] 8KB + B [256][32] 16KB} = 72 KB LDS.
//   Per iter: read frags(j+1) (8 A + 4 B ds_read_b128) || STG tile j+3
//   (2 A + 4 B gl_lds16 calls, 4KB each) || 32 MFMA(j); lgkm0; vmcnt(6)
//   (tile j+2's 6 calls stay in flight, j+1 guaranteed landed); s_barrier.
// Two resident blocks/CU hide each other's vmcnt/barrier stalls (proj8 was
// 1 block/CU -> fully exposed sync, MfmaUtil 34%).
//   n-tile 0 -> theta, 1 -> phi, 2..5 -> featsT[t][f][s]
// ---------------------------------------------------------------------------
__global__ __launch_bounds__(256, 2) void k_proj4(
    const unsigned short* __restrict__ batch16,
    const unsigned short* __restrict__ aT,
    const unsigned short* __restrict__ bT,
    const unsigned short* __restrict__ gT,
    const float* __restrict__ a_b, const float* __restrict__ b_b,
    const float* __restrict__ g_b,
    unsigned short* __restrict__ theta,
    unsigned short* __restrict__ phi,
    unsigned short* __restrict__ featsT) {
  const int K = FF;  // 1024
  __shared__ unsigned short Al[3][4096];  // [slot][128*32]  8 KB/slot
  __shared__ unsigned short Bl[3][8192];  // [slot][256*32] 16 KB/slot

  // XCD-chunked bijective grid: 3072 = 8 xcd * 64 mtl * 6 nt, nt fastest.
  const int lin = blockIdx.x;
  const int xcd = lin & 7, idx = lin >> 3;  // idx in [0,384)
  const int nt = idx % 6;
  const int mt = xcd * 64 + idx / 6;        // 128-row block-row, [0,512)
  const int m0 = mt * 128;

  const unsigned short* Wt;
  const float* bias;
  int mode, nf0 = 0;  // mode: 0 theta, 1 phi, 2 featsT
  if (nt == 0)      { Wt = aT; bias = a_b; mode = 0; }
  else if (nt == 1) { Wt = bT; bias = b_b; mode = 1; }
  else { nf0 = (nt - 2) * 256; Wt = gT + (size_t)nf0 * K; bias = g_b + nf0; mode = 2; }

  const int tid = threadIdx.x;
  const int lane = tid & 63, wn = tid >> 6;  // 4 waves, 1 x 4 grid
  const int lr = lane & 15, lq = lane >> 4;

  // Inverse-swizzled staging source coords, 4 KB granules (pattern verified
  // correct in R9's k_fused3). A tile: 2 granules; B tile: 4 granules.
  int srA[2], scA[2], srB[4], scB[4];
#pragma unroll
  for (int c = 0; c < 2; c++) {
    const unsigned ob = (unsigned)(c * 4096) + (unsigned)tid * 16u;
    const unsigned lob = ob ^ (((ob >> 9) & 1u) << 5);
    srA[c] = (int)(lob >> 6);           // row in [0,128)
    scA[c] = (int)((lob & 63u) >> 1);   // col elems
  }
#pragma unroll
  for (int c = 0; c < 4; c++) {
    const unsigned ob = (unsigned)(c * 4096) + (unsigned)tid * 16u;
    const unsigned lob = ob ^ (((ob >> 9) & 1u) << 5);
    srB[c] = (int)(lob >> 6);           // row in [0,256)
    scB[c] = (int)((lob & 63u) >> 1);
  }
  const int ldsb = wn * 512;  // wave-uniform dest base within a 4 KB granule

  const unsigned short* pA = batch16 + (size_t)m0 * K;
  const unsigned short* pB = Wt;

#define STG4(s_, k_)                                                         \
  do {                                                                       \
    _Pragma("unroll") for (int c = 0; c < 2; c++)                            \
        gl_lds16(pA + (size_t)srA[c] * K + (k_) + scA[c],                    \
                 &Al[s_][c * 2048 + ldsb]);                                  \
    _Pragma("unroll") for (int c = 0; c < 4; c++)                            \
        gl_lds16(pB + (size_t)srB[c] * K + (k_) + scB[c],                    \
                 &Bl[s_][c * 2048 + ldsb]);                                  \
  } while (0)

  floatx4 acc[8][4];
#pragma unroll
  for (int i = 0; i < 8; i++)
#pragma unroll
    for (int j = 0; j < 4; j++) acc[i][j] = (floatx4)0.0f;

  short8 fA0[8], fB0[4], fA1[8], fB1[4];

  // ---- Prologue: stage t0(slot0), t1(slot1); read frags(t0); stage t2.
  STG4(0, 0);
  STG4(1, 32);
  asm volatile("s_waitcnt vmcnt(6)" ::: "memory");  // t0 landed, t1 in flight
  __builtin_amdgcn_s_barrier();
#pragma unroll
  for (int i = 0; i < 8; i++)
    fA0[i] = frag_ld(Al[0], i * 16 + lr, lq);
#pragma unroll
  for (int i = 0; i < 4; i++)
    fB0[i] = frag_ld(Bl[0], wn * 64 + i * 16 + lr, lq);
  STG4(2, 64);
  asm volatile("s_waitcnt lgkmcnt(0)" ::: "memory");
  __builtin_amdgcn_sched_barrier(0);
  asm volatile("s_waitcnt vmcnt(6)" ::: "memory");  // t1 landed (t2 in flight)
  __builtin_amdgcn_s_barrier();

  int slR = 1, slW = 0, kst = 96;  // kst = k0 of tile j+3

  // Body for tile j: CUR frags -> MFMA; read NXT=frags(j+1); optional STG j+3.
#define PBODY4(CA, CB, NA, NB, DOSTG, VM)                                    \
  do {                                                                       \
    const unsigned short* Ah_ = Al[slR];                                     \
    const unsigned short* Bh_ = Bl[slR];                                     \
    _Pragma("unroll") for (int i_ = 0; i_ < 8; i_++)                         \
        NA[i_] = frag_ld(Ah_, i_ * 16 + lr, lq);                             \
    _Pragma("unroll") for (int i_ = 0; i_ < 4; i_++)                         \
        NB[i_] = frag_ld(Bh_, wn * 64 + i_ * 16 + lr, lq);                   \
    if (DOSTG) STG4(slW, kst);                                               \
    __builtin_amdgcn_s_setprio(1);                                           \
    _Pragma("unroll") for (int i_ = 0; i_ < 8; i_++)                         \
      _Pragma("unroll") for (int j_ = 0; j_ < 4; j_++)                       \
          acc[i_][j_] = __builtin_amdgcn_mfma_f32_16x16x32_bf16(             \
              CA[i_], CB[j_], acc[i_][j_], 0, 0, 0);                         \
    __builtin_amdgcn_s_setprio(0);                                           \
    asm volatile("s_waitcnt lgkmcnt(0)" ::: "memory");                       \
    __builtin_amdgcn_sched_barrier(0);                                       \
    asm volatile("s_waitcnt vmcnt(" VM ")" ::: "memory");                    \
    __builtin_amdgcn_s_barrier();                                            \
    slW = slR; slR = (slR == 2) ? 0 : slR + 1; kst += 32;                    \
  } while (0)

  for (int jt = 0; jt < 14; ++jt) {  // tiles j = 0..27
    PBODY4(fA0, fB0, fA1, fB1, 1, "6");
    PBODY4(fA1, fB1, fA0, fB0, 1, "6");
  }
  PBODY4(fA0, fB0, fA1, fB1, 1, "6");  // j=28: STG t31
  PBODY4(fA1, fB1, fA0, fB0, 0, "0");  // j=29: drain t31
  PBODY4(fA0, fB0, fA1, fB1, 0, "0");  // j=30: reads frags(31)
  // j=31: MFMA only
  __builtin_amdgcn_s_setprio(1);
#pragma unroll
  for (int i = 0; i < 8; i++)
#pragma unroll
    for (int j = 0; j < 4; j++)
      acc[i][j] = __builtin_amdgcn_mfma_f32_16x16x32_bf16(fA1[i], fB1[j],
                                                          acc[i][j], 0, 0, 0);
  __builtin_amdgcn_s_setprio(0);
#undef PBODY4
#undef STG4

  // Epilogue. C/D layout: col = lane&15 (lr), row = lq*4 + rr.
  if (mode == 2) {
    const int t = mt >> 1, sb = (mt & 1) * 128;
#pragma unroll
    for (int r = 0; r < 8; r++) {
      const int s0 = sb + r * 16 + lq * 4;  // s (within t), 4 contiguous
#pragma unroll
      for (int jj = 0; jj < 4; jj++) {
        const int cl = wn * 64 + jj * 16 + lr;
        const float bv = bias[cl];
        ushort4 h;
        h.x = f2bf(acc[r][jj][0] + bv);
        h.y = f2bf(acc[r][jj][1] + bv);
        h.z = f2bf(acc[r][jj][2] + bv);
        h.w = f2bf(acc[r][jj][3] + bv);
        *(ushort4*)&featsT[((size_t)t * FF + nf0 + cl) * SS + s0] = h;
      }
    }
  } else {
    unsigned short* outp = (mode == 0) ? theta : phi;
#pragma unroll
    for (int r = 0; r < 8; r++) {
      const int row0 = m0 + r * 16 + lq * 4;
#pragma unroll
      for (int jj = 0; jj < 4; jj++) {
        const int col = wn * 64 + jj * 16 + lr;
        const float bv = bias[col];
#pragma unroll
        for (int rr = 0; rr < 4; rr++)
          outp[(size_t)(row0 + rr) * AA + col] = f2bf(acc[r][jj][rr] + bv);
      }
    }
  }
}

// ---------------------------------------------------------------------------
// Fused projection GEMM, fp32-A FALLBACK (used only if workspace too small).
// ---------------------------------------------------------------------------
__global__ __launch_bounds__(256) void k_proj(
    const float* __restrict__ batch,
    const unsigned short* __restrict__ aT,
    const unsigned short* __restrict__ bT,
    const unsigned short* __restrict__ gT,
    const float* __restrict__ a_b, const float* __restrict__ b_b,
    const float* __restrict__ g_b,
    unsigned short* __restrict__ theta,
    unsigned short* __restrict__ phi,
    unsigned short* __restrict__ featsT) {
  const int K = FF;
  __shared__ unsigned short As[128 * 32];
  __shared__ unsigned short Bs[128 * 32];

  const int nt = blockIdx.x, mt = blockIdx.y;
  const int m0 = mt * 128;
  const unsigned short* Wt;
  const float* bias;
  int nloc0, mode;
  if (nt < 2)      { Wt = aT; bias = a_b; nloc0 = nt * 128;       mode = 0; }
  else if (nt < 4) { Wt = bT; bias = b_b; nloc0 = (nt - 2) * 128; mode = 1; }
  else             { Wt = gT; bias = g_b; nloc0 = (nt - 4) * 128; mode = 2; }

  const int tid = threadIdx.x;
  const int lane = tid & 63, wave = tid >> 6;
  const int wm = wave >> 1, wn = wave & 1;
  const int lr = lane & 15, lq = lane >> 4;

  floatx4 acc[4][4];
#pragma unroll
  for (int i = 0; i < 4; i++)
#pragma unroll
    for (int j = 0; j < 4; j++) acc[i][j] = (floatx4)0.0f;

  for (int k0 = 0; k0 < K; k0 += 32) {
    __syncthreads();
    {
      int sl = tid;
      gl_lds16(Wt + (size_t)(nloc0 + (sl >> 2)) * K + k0 + (sl & 3) * 8,
               &Bs[wave * 512]);
      sl = tid + 256;
      gl_lds16(Wt + (size_t)(nloc0 + (sl >> 2)) * K + k0 + (sl & 3) * 8,
               &Bs[2048 + wave * 512]);
    }
#pragma unroll
    for (int sgi = 0; sgi < 4; sgi++) {
      int g = sgi * 256 + tid;
      int row = g >> 3, c4 = g & 7;
      const floatx4 v =
          *(const floatx4*)(batch + (size_t)(m0 + row) * K + k0 + c4 * 4);
      ushort4 h;
      h.x = f2bf(v.x); h.y = f2bf(v.y); h.z = f2bf(v.z); h.w = f2bf(v.w);
      *(ushort4*)&As[row * 32 + c4 * 4] = h;
    }
    __syncthreads();

    short8 af[4], bfr[4];
#pragma unroll
    for (int i = 0; i < 4; i++)
      af[i] = *(const short8*)&As[(wm * 64 + i * 16 + lr) * 32 + lq * 8];
#pragma unroll
    for (int j = 0; j < 4; j++)
      bfr[j] = *(const short8*)&Bs[(wn * 64 + j * 16 + lr) * 32 + lq * 8];
#pragma unroll
    for (int i = 0; i < 4; i++)
#pragma unroll
      for (int j = 0; j < 4; j++)
        acc[i][j] = __builtin_amdgcn_mfma_f32_16x16x32_bf16(af[i], bfr[j],
                                                            acc[i][j], 0, 0, 0);
  }

#pragma unroll
  for (int i = 0; i < 4; i++) {
    const int row0 = wm * 64 + i * 16 + lq * 4;
#pragma unroll
    for (int j = 0; j < 4; j++) {
      const int col = wn * 64 + j * 16 + lr;
      const float bv = bias[nloc0 + col];
      if (mode == 2) {
        const int m = m0 + row0;
        const int t = m >> 8, s = m & 255;
        ushort4 h;
        h.x = f2bf(acc[i][j][0] + bv);
        h.y = f2bf(acc[i][j][1] + bv);
        h.z = f2bf(acc[i][j][2] + bv);
        h.w = f2bf(acc[i][j][3] + bv);
        *(ushort4*)&featsT[((size_t)t * FF + nloc0 + col) * SS + s] = h;
      } else {
        unsigned short* outp = (mode == 0) ? theta : phi;
#pragma unroll
        for (int rr = 0; rr < 4; rr++)
          outp[(size_t)(m0 + row0 + rr) * AA + nloc0 + col] =
              f2bf(acc[i][j][rr] + bv);
      }
    }
  }
}

// ---------------------------------------------------------------------------
// Fused attn+apply v2 (R8 VERIFIED VERSION — restored after fused3 regressed):
//   Phase 1: P = theta[t][mh*128..][:] @ phi[t]^T  (128x256 bf16 -> LDS P)
//   Phase 2: out = P @ featsT[t]^T / 512           (3-slot ring, vmcnt(2));
//            wait SKIPPED at T%8 in {0,1}, T>=8 (chunk-end store-queue proof).
// ---------------------------------------------------------------------------
__global__ __launch_bounds__(512) void k_fused2(
    const unsigned short* __restrict__ theta,
    const unsigned short* __restrict__ phi,
    const unsigned short* __restrict__ featsT,
    float* __restrict__ out) {
  __shared__ unsigned short ring[24576];   // 48 KB
  __shared__ unsigned short P[128 * 256];  // 64 KB, swizzled

  const int lin = blockIdx.x;
  const int xcd = lin & 7, idx = lin >> 3;  // idx in [0,64)
  const int t = xcd * 32 + (idx >> 1);
  const int mh = idx & 1;

  const int tid = threadIdx.x, lane = tid & 63, wave = tid >> 6;
  const int wm = wave >> 2, wn = wave & 3;  // 2 x 4 wave grid
  const int lr = lane & 15, lq = lane >> 4;

  const unsigned short* Ath = theta + ((size_t)t * SS + mh * 128) * AA;
  const unsigned short* Bph = phi + (size_t)t * SS * AA;
  const unsigned short* Bft = featsT + (size_t)t * FF * SS;

  const unsigned o = (unsigned)tid * 16u;
  const unsigned lo = o ^ (((o >> 9) & 1u) << 5);
  const int srow = (int)(lo >> 6);          // 0..127
  const int scol = (int)((lo & 63u) >> 1);  // 0..24 step 8
  const int ldsb = wave * 512;              // elems

  // ======== Phase 1: attn tile -> P ========
#define STG_P1(s_, k_)                                                       \
  do {                                                                       \
    gl_lds16(Ath + (size_t)srow * AA + (k_) + scol, &ring[(s_)*12288 + ldsb]); \
    gl_lds16(Bph + (size_t)srow * AA + (k_) + scol,                          \
             &ring[(s_)*12288 + 4096 + ldsb]);                               \
    gl_lds16(Bph + (size_t)(128 + srow) * AA + (k_) + scol,                  \
             &ring[(s_)*12288 + 8192 + ldsb]);                               \
  } while (0)

  floatx4 acc[4][4];
#pragma unroll
  for (int i = 0; i < 4; i++)
#pragma unroll
    for (int j = 0; j < 4; j++) acc[i][j] = (floatx4)0.0f;

  STG_P1(0, 0);
  STG_P1(1, 32);
  for (int k = 0; k < 8; ++k) {
    if (k < 7)
      asm volatile("s_waitcnt vmcnt(3)" ::: "memory");  // tile k landed
    else
      asm volatile("s_waitcnt vmcnt(0)" ::: "memory");
    __builtin_amdgcn_s_barrier();

    const unsigned short* Abase = &ring[(k & 1) * 12288];
    const unsigned short* Bbase = Abase + 4096;
    short8 af[4], bf4[4];
#pragma unroll
    for (int i = 0; i < 4; i++)
      af[i] = frag_ld(Abase, wm * 64 + i * 16 + lr, lq);
#pragma unroll
    for (int j = 0; j < 4; j++)
      bf4[j] = frag_ld(Bbase, wn * 64 + j * 16 + lr, lq);
    asm volatile("s_waitcnt lgkmcnt(0)" ::: "memory");
    __builtin_amdgcn_s_barrier();
    if (k + 2 < 8) STG_P1(k & 1, (k + 2) * 32);

    __builtin_amdgcn_s_setprio(1);
#pragma unroll
    for (int i = 0; i < 4; i++)
#pragma unroll
      for (int j = 0; j < 4; j++)
        acc[i][j] = __builtin_amdgcn_mfma_f32_16x16x32_bf16(af[i], bf4[j],
                                                            acc[i][j], 0, 0, 0);
    __builtin_amdgcn_s_setprio(0);
  }
#undef STG_P1

#pragma unroll
  for (int i = 0; i < 4; i++) {
#pragma unroll
    for (int j = 0; j < 4; j++) {
      const int colP = wn * 64 + j * 16 + lr;
#pragma unroll
      for (int rr = 0; rr < 4; rr++) {
        const int rowP = wm * 64 + i * 16 + lq * 4 + rr;
        const unsigned off =
            ((unsigned)(rowP * 256 + colP) * 2u) ^ ((unsigned)(rowP & 7) << 4);
        *(unsigned short*)((char*)P + off) = f2bf(acc[i][j][rr]);
      }
    }
  }
  __syncthreads();  // P published; all phase-1 ring reads complete

  // ======== Phase 2: out = P @ featsT^T / 512 ========
#define STG_P2(slot_, T_)                                                    \
  do {                                                                       \
    const int c_ = (T_) >> 3, k_ = ((T_)&7) * 32;                            \
    gl_lds16(Bft + (size_t)(c_ * 256 + srow) * SS + k_ + scol,               \
             &ring[(slot_)*8192 + ldsb]);                                    \
    gl_lds16(Bft + (size_t)(c_ * 256 + 128 + srow) * SS + k_ + scol,         \
             &ring[(slot_)*8192 + 4096 + ldsb]);                             \
  } while (0)

  STG_P2(0, 0);
  STG_P2(1, 1);

  const float inv = 1.0f / 512.0f;
  float* Ob = out + ((size_t)t * SS + mh * 128) * FF;

#pragma unroll
  for (int i = 0; i < 4; i++)
#pragma unroll
    for (int j = 0; j < 4; j++) acc[i][j] = (floatx4)0.0f;

  int slot = 0, slot2 = 2;
  for (int T = 0; T < 32; ++T) {
    if (T == 31) {
      asm volatile("s_waitcnt vmcnt(0)" ::: "memory");
    } else if (!(T >= 8 && (T & 7) < 2)) {
      asm volatile("s_waitcnt vmcnt(2)" ::: "memory");  // tile T landed
    }
    // else: skip — chunk-end stores guarantee STG(T) retired (see header)
    __builtin_amdgcn_s_barrier();

    const int k0 = (T & 7) * 32;
    const unsigned short* Bbase = &ring[slot * 8192];
    short8 af[4], bf4[4];
#pragma unroll
    for (int i = 0; i < 4; i++) {
      const int rowP = wm * 64 + i * 16 + lr;
      const unsigned off = ((unsigned)(rowP * 256 + k0 + lq * 8) * 2u) ^
                           ((unsigned)(rowP & 7) << 4);
      af[i] = *(const short8*)((const char*)P + off);
    }
#pragma unroll
    for (int j = 0; j < 4; j++)
      bf4[j] = frag_ld(Bbase, wn * 64 + j * 16 + lr, lq);
    if (T + 2 < 32) STG_P2(slot2, T + 2);

    __builtin_amdgcn_s_setprio(1);
#pragma unroll
    for (int i = 0; i < 4; i++)
#pragma unroll
      for (int j = 0; j < 4; j++)
        acc[i][j] = __builtin_amdgcn_mfma_f32_16x16x32_bf16(af[i], bf4[j],
                                                            acc[i][j], 0, 0, 0);
    __builtin_amdgcn_s_setprio(0);

    if ((T & 7) == 7) {  // f-chunk complete: write out, reset acc
      const int c = T >> 3;
#pragma unroll
      for (int i = 0; i < 4; i++) {
        const int row0 = wm * 64 + i * 16 + lq * 4;
#pragma unroll
        for (int j = 0; j < 4; j++) {
          const int col = c * 256 + wn * 64 + j * 16 + lr;
#pragma unroll
          for (int rr = 0; rr < 4; rr++)
            Ob[(size_t)(row0 + rr) * FF + col] = acc[i][j][rr] * inv;
          acc[i][j] = (floatx4)0.0f;
        }
      }
    }
    slot = (slot == 2) ? 0 : slot + 1;
    slot2 = (slot2 == 2) ? 0 : slot2 + 1;
  }
#undef STG_P2
}

// ---------------------------------------------------------------------------
extern "C" void kernel_launch(void* const* d_in, const int* in_sizes, int n_in,
                              void* d_out, int out_size, void* d_ws,
                              size_t ws_size, hipStream_t stream) {
  const float* batch = (const float*)d_in[0];
  const float* a_w   = (const float*)d_in[1];
  const float* a_b   = (const float*)d_in[2];
  const float* b_w   = (const float*)d_in[3];
  const float* b_b   = (const float*)d_in[4];
  const float* g_w   = (const float*)d_in[5];
  const float* g_b   = (const float*)d_in[6];
  float* out = (float*)d_out;

  // Workspace layout (bf16 elements).
  unsigned short* ws      = (unsigned short*)d_ws;
  unsigned short* aT      = ws;                                  // 256x1024
  unsigned short* bT      = aT + (size_t)AA * FF;                // 256x1024
  unsigned short* gT      = bT + (size_t)AA * FF;                // 1024x1024
  unsigned short* theta   = gT + (size_t)FF * FF;                // 65536x256
  unsigned short* phi     = theta + (size_t)TT * SS * AA;        // 65536x256
  unsigned short* featsT  = phi + (size_t)TT * SS * AA;          // [t][f][s]
  unsigned short* batch16 = featsT + (size_t)TT * FF * SS;       // 65536x1024

  const size_t need_b16 =
      ((size_t)2 * AA * FF + (size_t)FF * FF + (size_t)2 * TT * SS * AA +
       (size_t)TT * FF * SS + (size_t)TT * SS * FF) *
      sizeof(unsigned short);

  if (ws_size >= need_b16) {
    // One fused prep launch (cvt + 3 transposes), then pipelined GEMM.
    k_prep<<<dim3(3584), 256, 0, stream>>>(batch, a_w, b_w, g_w, aT, bT, gT,
                                           batch16);
    k_proj4<<<dim3(3072), 256, 0, stream>>>(batch16, aT, bT, gT, a_b, b_b,
                                            g_b, theta, phi, featsT);
  } else {
    // Fallback: fp32 in-kernel staging (previous verified path).
    dim3 tb(32, 8);
    k_transpose_cvt<<<dim3(32, 8),  tb, 0, stream>>>(a_w, aT, FF, AA);
    k_transpose_cvt<<<dim3(32, 8),  tb, 0, stream>>>(b_w, bT, FF, AA);
    k_transpose_cvt<<<dim3(32, 32), tb, 0, stream>>>(g_w, gT, FF, FF);
    k_proj<<<dim3(12, 512), 256, 0, stream>>>(batch, aT, bT, gT, a_b, b_b,
                                              g_b, theta, phi, featsT);
  }

  // Fused attn + apply v2 (R8 verified): no attn round-trip.
  k_fused2<<<dim3(512), 512, 0, stream>>>(theta, phi, featsT, out);
}

// Round 11
// 775.247 us; speedup vs baseline: 1.0750x; 1.0750x over previous
//
#include <hip/hip_runtime.h>
#include <stdint.h>

// Problem dims (fixed by the reference)
#define TT 256
#define SS 256
#define FF 1024
#define AA 256

typedef __attribute__((ext_vector_type(8))) short short8;
typedef __attribute__((ext_vector_type(8))) unsigned short ushort8v;
typedef __attribute__((ext_vector_type(4))) float floatx4;

// fp32 -> bf16 round-to-nearest-even
__device__ __forceinline__ unsigned short f2bf(float f) {
  unsigned int u = __float_as_uint(f);
  u += 0x7FFFu + ((u >> 16) & 1u);
  return (unsigned short)(u >> 16);
}

// async global->LDS, 16 B per lane; LDS dest = wave-uniform base + lane*16
__device__ __forceinline__ void gl_lds16(const unsigned short* g, unsigned short* l) {
  __builtin_amdgcn_global_load_lds(
      (__attribute__((address_space(1))) void*)(g),
      (__attribute__((address_space(3))) void*)(l), 16, 0, 0);
}

// swizzled LDS fragment read: logical (row, 16B-chunk lq) of a [R][32] bf16
// tile; phys byte = logical ^ ((bit9)<<5)  (st_16x32; 0 conflicts measured
// at this 64B row stride — do NOT reuse for other strides, see R7 lesson)
__device__ __forceinline__ short8 frag_ld(const unsigned short* base, int row,
                                          int lq) {
  unsigned l = (unsigned)(row * 64 + lq * 16);
  l ^= ((l >> 9) & 1u) << 5;
  return *(const short8*)((const char*)base + l);
}

// ---------------------------------------------------------------------------
// Fused prep: ONE launch does batch fp32->bf16 cvt (blocks 0..2047) and the
// three weight transposes WT[n][k] = bf16(W[k][n]) (blocks 2048..3583).
// ---------------------------------------------------------------------------
__global__ __launch_bounds__(256) void k_prep(
    const float* __restrict__ batch, const float* __restrict__ a_w,
    const float* __restrict__ b_w, const float* __restrict__ g_w,
    unsigned short* __restrict__ aT, unsigned short* __restrict__ bT,
    unsigned short* __restrict__ gT, unsigned short* __restrict__ batch16) {
  __shared__ float tile[32][33];
  const int b = blockIdx.x;
  const int tid = threadIdx.x;

  if (b < 2048) {
    const long n8 = (long)TT * SS * FF / 8;
    long i = (long)b * 256 + tid;
    const long stride = 2048L * 256;
    for (; i < n8; i += stride) {
      const floatx4 v0 = *(const floatx4*)(batch + i * 8);
      const floatx4 v1 = *(const floatx4*)(batch + i * 8 + 4);
      ushort8v h;
      h[0] = f2bf(v0.x); h[1] = f2bf(v0.y); h[2] = f2bf(v0.z); h[3] = f2bf(v0.w);
      h[4] = f2bf(v1.x); h[5] = f2bf(v1.y); h[6] = f2bf(v1.z); h[7] = f2bf(v1.w);
      *(ushort8v*)(batch16 + i * 8) = h;
    }
    return;
  }

  int tb = b - 2048;
  const float* W;
  unsigned short* WT;
  int N, bk, bn;
  if (tb < 256)      { W = a_w; WT = aT; N = AA; bk = (tb & 31) * 32; bn = (tb >> 5) * 32; }
  else if (tb < 512) { tb -= 256; W = b_w; WT = bT; N = AA; bk = (tb & 31) * 32; bn = (tb >> 5) * 32; }
  else               { tb -= 512; W = g_w; WT = gT; N = FF; bk = (tb & 31) * 32; bn = (tb >> 5) * 32; }
  const int K = FF;
  const int tx = tid & 31, ty = tid >> 5;
  for (int i = ty; i < 32; i += 8)
    tile[i][tx] = W[(size_t)(bk + i) * N + bn + tx];
  __syncthreads();
  for (int i = ty; i < 32; i += 8)
    WT[(size_t)(bn + i) * K + bk + tx] = f2bf(tile[tx][i]);
}

// ---------------------------------------------------------------------------
// Weight transpose (fallback path only).
// ---------------------------------------------------------------------------
__global__ void k_transpose_cvt(const float* __restrict__ W,
                                unsigned short* __restrict__ WT,
                                int K, int N) {
  __shared__ float tile[32][33];
  const int bk = blockIdx.x * 32, bn = blockIdx.y * 32;
  const int tx = threadIdx.x, ty = threadIdx.y;
  for (int i = ty; i < 32; i += 8)
    tile[i][tx] = W[(size_t)(bk + i) * N + bn + tx];
  __syncthreads();
  for (int i = ty; i < 32; i += 8)
    WT[(size_t)(bn + i) * K + bk + tx] = f2bf(tile[tx][i]);
}

// ---------------------------------------------------------------------------
// Projection GEMM, 256x256 tile, 2-K-tiles-per-barrier pipeline:
//   4-slot ring of verified [128][32] tiles (128 KB LDS, 1 block/CU, 8 waves).
//   16 iters; iter J: {read frags(2J) || STG tiles 2J+2,2J+3 -> lgkm0 ->
//   read frags(2J+1) || 32 MFMA(2J) -> lgkm0 -> 32 MFMA(2J+1) -> vmcnt(0)
//   (issued ~2300 cyc earlier: free drain) -> ONE s_barrier}.
//   Slot audit: iter J reads slots {2J,2J+1}&3, writes {2J+2,2J+3}&3 —
//   disjoint; write targets freed by the previous end-of-iter barrier.
//   Halves barrier/wait count vs R8 proj8 (32 -> 16 sync intervals).
//   n-tile 0 -> theta, 1 -> phi, 2..5 -> featsT[t][f][s]
// ---------------------------------------------------------------------------
__global__ __launch_bounds__(512, 2) void k_proj8(
    const unsigned short* __restrict__ batch16,
    const unsigned short* __restrict__ aT,
    const unsigned short* __restrict__ bT,
    const unsigned short* __restrict__ gT,
    const float* __restrict__ a_b, const float* __restrict__ b_b,
    const float* __restrict__ g_b,
    unsigned short* __restrict__ theta,
    unsigned short* __restrict__ phi,
    unsigned short* __restrict__ featsT) {
  const int K = FF;  // 1024
  __shared__ unsigned short Al[4][2][4096];  // [slot][m-half][128*32] 64 KB
  __shared__ unsigned short Bl[4][2][4096];  // [slot][n-half][128*32] 64 KB

  // XCD-chunked bijective grid: xcd = lin&7 (round-robin dispatch);
  // nt fastest -> 6 same-A-panel blocks adjacent on one XCD's L2.
  const int lin = blockIdx.x;
  const int xcd = lin & 7, idx = lin >> 3;
  const int nt = idx % 6;
  const int mt = xcd * 32 + idx / 6;
  const int m0 = mt * 256;

  const unsigned short* Wt;
  const float* bias;
  int mode, nf0 = 0;  // mode: 0 theta, 1 phi, 2 featsT
  if (nt == 0)      { Wt = aT; bias = a_b; mode = 0; }
  else if (nt == 1) { Wt = bT; bias = b_b; mode = 1; }
  else { nf0 = (nt - 2) * 256; Wt = gT + (size_t)nf0 * K; bias = g_b + nf0; mode = 2; }

  const int tid = threadIdx.x;
  const int lane = tid & 63, wave = tid >> 6;
  const int wm = wave >> 2, wn = wave & 3;   // 2 x 4 wave grid
  const int lr = lane & 15, lq = lane >> 4;
  const int bh = wn >> 1;                    // which B half this wave reads
  const int bn0 = (wn & 1) * 64;             // row base within B half

  // Staging source coords: LDS dest linear; SOURCE inverse-swizzled.
  const unsigned o = (unsigned)tid * 16u;
  const unsigned lo = o ^ (((o >> 9) & 1u) << 5);
  const int srow = (int)(lo >> 6);          // 0..127
  const int scol = (int)((lo & 63u) >> 1);  // 0..24 step 8
  const unsigned aoff = (unsigned)(srow * K + scol);  // 32-bit lane offset
  const int ldsb = wave * 512;              // wave-uniform dest base (elems)

  const unsigned short* pA0 = batch16 + (size_t)m0 * K;
  const unsigned short* pA1 = pA0 + (size_t)128 * K;
  const unsigned short* pB0 = Wt;
  const unsigned short* pB1 = Wt + (size_t)128 * K;

  floatx4 acc[8][4];
#pragma unroll
  for (int i = 0; i < 8; i++)
#pragma unroll
    for (int j = 0; j < 4; j++) acc[i][j] = (floatx4)0.0f;

  short8 fA0[8], fB0[4], fA1[8], fB1[4];

#define STG1(s_, k_)                                   \
  do {                                                 \
    gl_lds16(pA0 + aoff + (k_), &Al[s_][0][ldsb]);     \
    gl_lds16(pA1 + aoff + (k_), &Al[s_][1][ldsb]);     \
    gl_lds16(pB0 + aoff + (k_), &Bl[s_][0][ldsb]);     \
    gl_lds16(pB1 + aoff + (k_), &Bl[s_][1][ldsb]);     \
  } while (0)

  // ---- Prologue: stage tiles 0 -> slot0, 1 -> slot1; drain; barrier.
  STG1(0, 0);
  STG1(1, 32);
  asm volatile("s_waitcnt vmcnt(0)" ::: "memory");
  __builtin_amdgcn_s_barrier();

  // 16 iters, 2 K-tiles each. Tiles 2J, 2J+1 in slots (2J)&3, (2J+1)&3.
  for (int J = 0; J < 16; ++J) {
    const int s0 = (2 * J) & 3, s1 = (2 * J + 1) & 3;
    const unsigned short* A0h = Al[s0][wm];
    const unsigned short* B0h = Bl[s0][bh];
    const unsigned short* A1h = Al[s1][wm];
    const unsigned short* B1h = Bl[s1][bh];

    // read frags of tile 2J
#pragma unroll
    for (int i = 0; i < 8; i++)
      fA0[i] = frag_ld(A0h, ((i >> 2) * 64) + (i & 3) * 16 + lr, lq);
#pragma unroll
    for (int i = 0; i < 4; i++)
      fB0[i] = frag_ld(B0h, bn0 + i * 16 + lr, lq);
    // issue stages for tiles 2J+2, 2J+3 (slots freed by previous barrier)
    if (J < 15) {
      STG1((2 * J + 2) & 3, (2 * J + 2) * 32);
      STG1((2 * J + 3) & 3, (2 * J + 3) * 32);
    }
    asm volatile("s_waitcnt lgkmcnt(0)" ::: "memory");
    __builtin_amdgcn_sched_barrier(0);

    // read frags of tile 2J+1 (overlaps MFMA on tile 2J)
#pragma unroll
    for (int i = 0; i < 8; i++)
      fA1[i] = frag_ld(A1h, ((i >> 2) * 64) + (i & 3) * 16 + lr, lq);
#pragma unroll
    for (int i = 0; i < 4; i++)
      fB1[i] = frag_ld(B1h, bn0 + i * 16 + lr, lq);

    __builtin_amdgcn_s_setprio(1);
#pragma unroll
    for (int i = 0; i < 8; i++)
#pragma unroll
      for (int j = 0; j < 4; j++)
        acc[i][j] = __builtin_amdgcn_mfma_f32_16x16x32_bf16(fA0[i], fB0[j],
                                                            acc[i][j], 0, 0, 0);
    __builtin_amdgcn_s_setprio(0);
    asm volatile("s_waitcnt lgkmcnt(0)" ::: "memory");
    __builtin_amdgcn_sched_barrier(0);
    __builtin_amdgcn_s_setprio(1);
#pragma unroll
    for (int i = 0; i < 8; i++)
#pragma unroll
      for (int j = 0; j < 4; j++)
        acc[i][j] = __builtin_amdgcn_mfma_f32_16x16x32_bf16(fA1[i], fB1[j],
                                                            acc[i][j], 0, 0, 0);
    __builtin_amdgcn_s_setprio(0);

    if (J < 15) {
      // stages were issued ~2300 cyc ago (24 ds_reads + 64 MFMA): free drain
      asm volatile("s_waitcnt vmcnt(0)" ::: "memory");
      __builtin_amdgcn_s_barrier();
    }
  }
#undef STG1

  // Epilogue. C/D layout: col = lane&15 (lr), row = lq*4 + rr.
  if (mode == 2) {
#pragma unroll
    for (int r = 0; r < 8; r++) {
      const int s0 = wm * 128 + r * 16 + lq * 4;  // s (within t), 4 contiguous
#pragma unroll
      for (int jj = 0; jj < 4; jj++) {
        const int cl = wn * 64 + jj * 16 + lr;
        const float bv = bias[cl];
        ushort4 h;
        h.x = f2bf(acc[r][jj][0] + bv);
        h.y = f2bf(acc[r][jj][1] + bv);
        h.z = f2bf(acc[r][jj][2] + bv);
        h.w = f2bf(acc[r][jj][3] + bv);
        *(ushort4*)&featsT[((size_t)mt * FF + nf0 + cl) * SS + s0] = h;
      }
    }
  } else {
    unsigned short* outp = (mode == 0) ? theta : phi;
#pragma unroll
    for (int r = 0; r < 8; r++) {
      const int row0 = m0 + wm * 128 + r * 16 + lq * 4;
#pragma unroll
      for (int jj = 0; jj < 4; jj++) {
        const int col = wn * 64 + jj * 16 + lr;
        const float bv = bias[col];
#pragma unroll
        for (int rr = 0; rr < 4; rr++)
          outp[(size_t)(row0 + rr) * AA + col] = f2bf(acc[r][jj][rr] + bv);
      }
    }
  }
}

// ---------------------------------------------------------------------------
// Fused projection GEMM, fp32-A FALLBACK (used only if workspace too small).
// ---------------------------------------------------------------------------
__global__ __launch_bounds__(256) void k_proj(
    const float* __restrict__ batch,
    const unsigned short* __restrict__ aT,
    const unsigned short* __restrict__ bT,
    const unsigned short* __restrict__ gT,
    const float* __restrict__ a_b, const float* __restrict__ b_b,
    const float* __restrict__ g_b,
    unsigned short* __restrict__ theta,
    unsigned short* __restrict__ phi,
    unsigned short* __restrict__ featsT) {
  const int K = FF;
  __shared__ unsigned short As[128 * 32];
  __shared__ unsigned short Bs[128 * 32];

  const int nt = blockIdx.x, mt = blockIdx.y;
  const int m0 = mt * 128;
  const unsigned short* Wt;
  const float* bias;
  int nloc0, mode;
  if (nt < 2)      { Wt = aT; bias = a_b; nloc0 = nt * 128;       mode = 0; }
  else if (nt < 4) { Wt = bT; bias = b_b; nloc0 = (nt - 2) * 128; mode = 1; }
  else             { Wt = gT; bias = g_b; nloc0 = (nt - 4) * 128; mode = 2; }

  const int tid = threadIdx.x;
  const int lane = tid & 63, wave = tid >> 6;
  const int wm = wave >> 1, wn = wave & 1;
  const int lr = lane & 15, lq = lane >> 4;

  floatx4 acc[4][4];
#pragma unroll
  for (int i = 0; i < 4; i++)
#pragma unroll
    for (int j = 0; j < 4; j++) acc[i][j] = (floatx4)0.0f;

  for (int k0 = 0; k0 < K; k0 += 32) {
    __syncthreads();
    {
      int sl = tid;
      gl_lds16(Wt + (size_t)(nloc0 + (sl >> 2)) * K + k0 + (sl & 3) * 8,
               &Bs[wave * 512]);
      sl = tid + 256;
      gl_lds16(Wt + (size_t)(nloc0 + (sl >> 2)) * K + k0 + (sl & 3) * 8,
               &Bs[2048 + wave * 512]);
    }
#pragma unroll
    for (int sgi = 0; sgi < 4; sgi++) {
      int g = sgi * 256 + tid;
      int row = g >> 3, c4 = g & 7;
      const floatx4 v =
          *(const floatx4*)(batch + (size_t)(m0 + row) * K + k0 + c4 * 4);
      ushort4 h;
      h.x = f2bf(v.x); h.y = f2bf(v.y); h.z = f2bf(v.z); h.w = f2bf(v.w);
      *(ushort4*)&As[row * 32 + c4 * 4] = h;
    }
    __syncthreads();

    short8 af[4], bfr[4];
#pragma unroll
    for (int i = 0; i < 4; i++)
      af[i] = *(const short8*)&As[(wm * 64 + i * 16 + lr) * 32 + lq * 8];
#pragma unroll
    for (int j = 0; j < 4; j++)
      bfr[j] = *(const short8*)&Bs[(wn * 64 + j * 16 + lr) * 32 + lq * 8];
#pragma unroll
    for (int i = 0; i < 4; i++)
#pragma unroll
      for (int j = 0; j < 4; j++)
        acc[i][j] = __builtin_amdgcn_mfma_f32_16x16x32_bf16(af[i], bfr[j],
                                                            acc[i][j], 0, 0, 0);
  }

#pragma unroll
  for (int i = 0; i < 4; i++) {
    const int row0 = wm * 64 + i * 16 + lq * 4;
#pragma unroll
    for (int j = 0; j < 4; j++) {
      const int col = wn * 64 + j * 16 + lr;
      const float bv = bias[nloc0 + col];
      if (mode == 2) {
        const int m = m0 + row0;
        const int t = m >> 8, s = m & 255;
        ushort4 h;
        h.x = f2bf(acc[i][j][0] + bv);
        h.y = f2bf(acc[i][j][1] + bv);
        h.z = f2bf(acc[i][j][2] + bv);
        h.w = f2bf(acc[i][j][3] + bv);
        *(ushort4*)&featsT[((size_t)t * FF + nloc0 + col) * SS + s] = h;
      } else {
        unsigned short* outp = (mode == 0) ? theta : phi;
#pragma unroll
        for (int rr = 0; rr < 4; rr++)
          outp[(size_t)(m0 + row0 + rr) * AA + nloc0 + col] =
              f2bf(acc[i][j][rr] + bv);
      }
    }
  }
}

// ---------------------------------------------------------------------------
// Fused attn+apply v2 (R8 VERIFIED VERSION — unchanged):
//   Phase 1: P = theta[t][mh*128..][:] @ phi[t]^T  (128x256 bf16 -> LDS P)
//   Phase 2: out = P @ featsT[t]^T / 512           (3-slot ring, vmcnt(2));
//            wait SKIPPED at T%8 in {0,1}, T>=8 (chunk-end store-queue proof).
// ---------------------------------------------------------------------------
__global__ __launch_bounds__(512) void k_fused2(
    const unsigned short* __restrict__ theta,
    const unsigned short* __restrict__ phi,
    const unsigned short* __restrict__ featsT,
    float* __restrict__ out) {
  __shared__ unsigned short ring[24576];   // 48 KB
  __shared__ unsigned short P[128 * 256];  // 64 KB, swizzled

  const int lin = blockIdx.x;
  const int xcd = lin & 7, idx = lin >> 3;  // idx in [0,64)
  const int t = xcd * 32 + (idx >> 1);
  const int mh = idx & 1;

  const int tid = threadIdx.x, lane = tid & 63, wave = tid >> 6;
  const int wm = wave >> 2, wn = wave & 3;  // 2 x 4 wave grid
  const int lr = lane & 15, lq = lane >> 4;

  const unsigned short* Ath = theta + ((size_t)t * SS + mh * 128) * AA;
  const unsigned short* Bph = phi + (size_t)t * SS * AA;
  const unsigned short* Bft = featsT + (size_t)t * FF * SS;

  const unsigned o = (unsigned)tid * 16u;
  const unsigned lo = o ^ (((o >> 9) & 1u) << 5);
  const int srow = (int)(lo >> 6);          // 0..127
  const int scol = (int)((lo & 63u) >> 1);  // 0..24 step 8
  const int ldsb = wave * 512;              // elems

  // ======== Phase 1: attn tile -> P ========
#define STG_P1(s_, k_)                                                       \
  do {                                                                       \
    gl_lds16(Ath + (size_t)srow * AA + (k_) + scol, &ring[(s_)*12288 + ldsb]); \
    gl_lds16(Bph + (size_t)srow * AA + (k_) + scol,                          \
             &ring[(s_)*12288 + 4096 + ldsb]);                               \
    gl_lds16(Bph + (size_t)(128 + srow) * AA + (k_) + scol,                  \
             &ring[(s_)*12288 + 8192 + ldsb]);                               \
  } while (0)

  floatx4 acc[4][4];
#pragma unroll
  for (int i = 0; i < 4; i++)
#pragma unroll
    for (int j = 0; j < 4; j++) acc[i][j] = (floatx4)0.0f;

  STG_P1(0, 0);
  STG_P1(1, 32);
  for (int k = 0; k < 8; ++k) {
    if (k < 7)
      asm volatile("s_waitcnt vmcnt(3)" ::: "memory");  // tile k landed
    else
      asm volatile("s_waitcnt vmcnt(0)" ::: "memory");
    __builtin_amdgcn_s_barrier();

    const unsigned short* Abase = &ring[(k & 1) * 12288];
    const unsigned short* Bbase = Abase + 4096;
    short8 af[4], bf4[4];
#pragma unroll
    for (int i = 0; i < 4; i++)
      af[i] = frag_ld(Abase, wm * 64 + i * 16 + lr, lq);
#pragma unroll
    for (int j = 0; j < 4; j++)
      bf4[j] = frag_ld(Bbase, wn * 64 + j * 16 + lr, lq);
    asm volatile("s_waitcnt lgkmcnt(0)" ::: "memory");
    __builtin_amdgcn_s_barrier();
    if (k + 2 < 8) STG_P1(k & 1, (k + 2) * 32);

    __builtin_amdgcn_s_setprio(1);
#pragma unroll
    for (int i = 0; i < 4; i++)
#pragma unroll
      for (int j = 0; j < 4; j++)
        acc[i][j] = __builtin_amdgcn_mfma_f32_16x16x32_bf16(af[i], bf4[j],
                                                            acc[i][j], 0, 0, 0);
    __builtin_amdgcn_s_setprio(0);
  }
#undef STG_P1

#pragma unroll
  for (int i = 0; i < 4; i++) {
#pragma unroll
    for (int j = 0; j < 4; j++) {
      const int colP = wn * 64 + j * 16 + lr;
#pragma unroll
      for (int rr = 0; rr < 4; rr++) {
        const int rowP = wm * 64 + i * 16 + lq * 4 + rr;
        const unsigned off =
            ((unsigned)(rowP * 256 + colP) * 2u) ^ ((unsigned)(rowP & 7) << 4);
        *(unsigned short*)((char*)P + off) = f2bf(acc[i][j][rr]);
      }
    }
  }
  __syncthreads();  // P published; all phase-1 ring reads complete

  // ======== Phase 2: out = P @ featsT^T / 512 ========
#define STG_P2(slot_, T_)                                                    \
  do {                                                                       \
    const int c_ = (T_) >> 3, k_ = ((T_)&7) * 32;                            \
    gl_lds16(Bft + (size_t)(c_ * 256 + srow) * SS + k_ + scol,               \
             &ring[(slot_)*8192 + ldsb]);                                    \
    gl_lds16(Bft + (size_t)(c_ * 256 + 128 + srow) * SS + k_ + scol,         \
             &ring[(slot_)*8192 + 4096 + ldsb]);                             \
  } while (0)

  STG_P2(0, 0);
  STG_P2(1, 1);

  const float inv = 1.0f / 512.0f;
  float* Ob = out + ((size_t)t * SS + mh * 128) * FF;

#pragma unroll
  for (int i = 0; i < 4; i++)
#pragma unroll
    for (int j = 0; j < 4; j++) acc[i][j] = (floatx4)0.0f;

  int slot = 0, slot2 = 2;
  for (int T = 0; T < 32; ++T) {
    if (T == 31) {
      asm volatile("s_waitcnt vmcnt(0)" ::: "memory");
    } else if (!(T >= 8 && (T & 7) < 2)) {
      asm volatile("s_waitcnt vmcnt(2)" ::: "memory");  // tile T landed
    }
    // else: skip — chunk-end stores guarantee STG(T) retired (see header)
    __builtin_amdgcn_s_barrier();

    const int k0 = (T & 7) * 32;
    const unsigned short* Bbase = &ring[slot * 8192];
    short8 af[4], bf4[4];
#pragma unroll
    for (int i = 0; i < 4; i++) {
      const int rowP = wm * 64 + i * 16 + lr;
      const unsigned off = ((unsigned)(rowP * 256 + k0 + lq * 8) * 2u) ^
                           ((unsigned)(rowP & 7) << 4);
      af[i] = *(const short8*)((const char*)P + off);
    }
#pragma unroll
    for (int j = 0; j < 4; j++)
      bf4[j] = frag_ld(Bbase, wn * 64 + j * 16 + lr, lq);
    if (T + 2 < 32) STG_P2(slot2, T + 2);

    __builtin_amdgcn_s_setprio(1);
#pragma unroll
    for (int i = 0; i < 4; i++)
#pragma unroll
      for (int j = 0; j < 4; j++)
        acc[i][j] = __builtin_amdgcn_mfma_f32_16x16x32_bf16(af[i], bf4[j],
                                                            acc[i][j], 0, 0, 0);
    __builtin_amdgcn_s_setprio(0);

    if ((T & 7) == 7) {  // f-chunk complete: write out, reset acc
      const int c = T >> 3;
#pragma unroll
      for (int i = 0; i < 4; i++) {
        const int row0 = wm * 64 + i * 16 + lq * 4;
#pragma unroll
        for (int j = 0; j < 4; j++) {
          const int col = c * 256 + wn * 64 + j * 16 + lr;
#pragma unroll
          for (int rr = 0; rr < 4; rr++)
            Ob[(size_t)(row0 + rr) * FF + col] = acc[i][j][rr] * inv;
          acc[i][j] = (floatx4)0.0f;
        }
      }
    }
    slot = (slot == 2) ? 0 : slot + 1;
    slot2 = (slot2 == 2) ? 0 : slot2 + 1;
  }
#undef STG_P2
}

// ---------------------------------------------------------------------------
extern "C" void kernel_launch(void* const* d_in, const int* in_sizes, int n_in,
                              void* d_out, int out_size, void* d_ws,
                              size_t ws_size, hipStream_t stream) {
  const float* batch = (const float*)d_in[0];
  const float* a_w   = (const float*)d_in[1];
  const float* a_b   = (const float*)d_in[2];
  const float* b_w   = (const float*)d_in[3];
  const float* b_b   = (const float*)d_in[4];
  const float* g_w   = (const float*)d_in[5];
  const float* g_b   = (const float*)d_in[6];
  float* out = (float*)d_out;

  // Workspace layout (bf16 elements).
  unsigned short* ws      = (unsigned short*)d_ws;
  unsigned short* aT      = ws;                                  // 256x1024
  unsigned short* bT      = aT + (size_t)AA * FF;                // 256x1024
  unsigned short* gT      = bT + (size_t)AA * FF;                // 1024x1024
  unsigned short* theta   = gT + (size_t)FF * FF;                // 65536x256
  unsigned short* phi     = theta + (size_t)TT * SS * AA;        // 65536x256
  unsigned short* featsT  = phi + (size_t)TT * SS * AA;          // [t][f][s]
  unsigned short* batch16 = featsT + (size_t)TT * FF * SS;       // 65536x1024

  const size_t need_b16 =
      ((size_t)2 * AA * FF + (size_t)FF * FF + (size_t)2 * TT * SS * AA +
       (size_t)TT * FF * SS + (size_t)TT * SS * FF) *
      sizeof(unsigned short);

  if (ws_size >= need_b16) {
    // One fused prep launch (cvt + 3 transposes), then pipelined GEMM.
    k_prep<<<dim3(3584), 256, 0, stream>>>(batch, a_w, b_w, g_w, aT, bT, gT,
                                           batch16);
    k_proj8<<<dim3(1536), 512, 0, stream>>>(batch16, aT, bT, gT, a_b, b_b,
                                            g_b, theta, phi, featsT);
  } else {
    // Fallback: fp32 in-kernel staging (previous verified path).
    dim3 tb(32, 8);
    k_transpose_cvt<<<dim3(32, 8),  tb, 0, stream>>>(a_w, aT, FF, AA);
    k_transpose_cvt<<<dim3(32, 8),  tb, 0, stream>>>(b_w, bT, FF, AA);
    k_transpose_cvt<<<dim3(32, 32), tb, 0, stream>>>(g_w, gT, FF, FF);
    k_proj<<<dim3(12, 512), 256, 0, stream>>>(batch, aT, bT, gT, a_b, b_b,
                                              g_b, theta, phi, featsT);
  }

  // Fused attn + apply v2 (R8 verified): no attn round-trip.
  k_fused2<<<dim3(512), 512, 0, stream>>>(theta, phi, featsT, out);
}